// Round 1
// baseline (68.369 us; speedup 1.0000x reference)
//
#include <hip/hip_runtime.h>

// Net_33294586479043: 2-layer GCN ending in log_softmax(out, axis=1) where
// out has shape [N, 1]. log_softmax over a size-1 axis is identically 0 for
// any finite input, and every intermediate value in the reference is finite
// (self-loops guarantee deg >= 1, inputs are random normals). So the exact
// reference output is 100000 zeros — the whole GCN is dead code w.r.t. d_out.
// The harness poisons d_out with 0xAA before each timed replay, so we must
// re-write the zeros on every call; that is the ONLY required work.

__global__ void zero_out_kernel(float* __restrict__ out, int n) {
    const int tid    = blockIdx.x * blockDim.x + threadIdx.x;
    const int stride = gridDim.x * blockDim.x;

    // Vectorized 16B stores; d_out is a device allocation (>=256B aligned).
    float4* __restrict__ o4 = reinterpret_cast<float4*>(out);
    const int n4 = n >> 2;
    for (int j = tid; j < n4; j += stride) {
        o4[j] = make_float4(0.0f, 0.0f, 0.0f, 0.0f);
    }
    // Scalar tail (n=100000 is divisible by 4, so this is normally empty).
    for (int j = (n4 << 2) + tid; j < n; j += stride) {
        out[j] = 0.0f;
    }
}

extern "C" void kernel_launch(void* const* d_in, const int* in_sizes, int n_in,
                              void* d_out, int out_size, void* d_ws, size_t ws_size,
                              hipStream_t stream) {
    (void)d_in; (void)in_sizes; (void)n_in; (void)d_ws; (void)ws_size;

    float* out = reinterpret_cast<float*>(d_out);
    const int n = out_size;              // 100000 floats
    const int block = 256;
    const int n4 = (n + 3) >> 2;         // 25000 float4 stores
    const int grid = (n4 + block - 1) / block;  // 98 blocks

    zero_out_kernel<<<grid, block, 0, stream>>>(out, n);
}